// Round 1
// baseline (232.195 us; speedup 1.0000x reference)
//
#include <hip/hip_runtime.h>
#include <math.h>

// ---- problem constants ----
#define NCOL   114688      // P*PED = 224*512
#define NCOL4  28672       // NCOL/4
#define KTOT   384         // EMB
#define NCH    8           // k-chunks for the GEMV
#define KCH    48          // KTOT/NCH
#define NROWS  448         // B * 224
#define PED    512

// ws layout (in floats)
#define OFF_PART 0
#define OFF_PE   (NCH * 2 * NCOL)          // 1,835,008
#define OFF_HA   (OFF_PE + 2 * NCOL)       // 2,064,384
#define OFF_HB   (OFF_HA + NROWS * 256)    // 2,179,072
#define OFF_AB   (OFF_HB + NROWS * 256)    // 2,293,760
#define OFF_BB   (OFF_AB + NROWS * 1024)   // 2,752,512
// total: 3,211,264 floats = 12.85 MB

// K1: partial GEMV  pe_part[ch][b][col] = sum_{k in chunk} cond[b][k] * W[k][col]
__global__ __launch_bounds__(256) void k_gemv(const float* __restrict__ cond,
                                              const float* __restrict__ W,
                                              float* __restrict__ part) {
    const int col4 = blockIdx.x * 256 + threadIdx.x;   // [0, 28672)
    const int ch   = blockIdx.y;
    const int k0   = ch * KCH;
    __shared__ float cs[2 * KCH];
    if (threadIdx.x < 2 * KCH) {
        int b = threadIdx.x / KCH;
        int kk = threadIdx.x - b * KCH;
        cs[threadIdx.x] = cond[b * KTOT + k0 + kk];
    }
    __syncthreads();
    const float4* __restrict__ W4 = (const float4*)W;
    float4 a0 = make_float4(0.f, 0.f, 0.f, 0.f);
    float4 a1 = make_float4(0.f, 0.f, 0.f, 0.f);
#pragma unroll 8
    for (int kk = 0; kk < KCH; ++kk) {
        float4 w = W4[(size_t)(k0 + kk) * NCOL4 + col4];
        float c0 = cs[kk];
        float c1 = cs[KCH + kk];
        a0.x = fmaf(c0, w.x, a0.x); a0.y = fmaf(c0, w.y, a0.y);
        a0.z = fmaf(c0, w.z, a0.z); a0.w = fmaf(c0, w.w, a0.w);
        a1.x = fmaf(c1, w.x, a1.x); a1.y = fmaf(c1, w.y, a1.y);
        a1.z = fmaf(c1, w.z, a1.z); a1.w = fmaf(c1, w.w, a1.w);
    }
    float4* p4 = (float4*)part;
    p4[((size_t)ch * 2 + 0) * NCOL4 + col4] = a0;
    p4[((size_t)ch * 2 + 1) * NCOL4 + col4] = a1;
}

// K1b: pe[b][col] = b_proj[col] + sum_ch part[ch][b][col]
__global__ __launch_bounds__(256) void k_reduce(const float* __restrict__ part,
                                                const float* __restrict__ bproj,
                                                float* __restrict__ pe) {
    const int c4 = blockIdx.x * 256 + threadIdx.x;   // [0, 28672)
    const int b  = blockIdx.y;
    const float4* p4 = (const float4*)part;
    float4 s = ((const float4*)bproj)[c4];
#pragma unroll
    for (int ch = 0; ch < NCH; ++ch) {
        float4 v = p4[((size_t)ch * 2 + b) * NCOL4 + c4];
        s.x += v.x; s.y += v.y; s.z += v.z; s.w += v.w;
    }
    ((float4*)pe)[(size_t)b * NCOL4 + c4] = s;
}

__device__ __forceinline__ float gelu_erf(float x) {
    return 0.5f * x * (1.0f + erff(x * 0.70710678118654752440f));
}

// K2: hA = gelu(pe @ WA1 + bA1), hB = gelu(pe @ WB1 + bB1)   (448x512 @ 512x256)
__global__ __launch_bounds__(256) void k_dec1(const float* __restrict__ pe,
                                              const float* __restrict__ WA1,
                                              const float* __restrict__ bA1,
                                              const float* __restrict__ WB1,
                                              const float* __restrict__ bB1,
                                              float* __restrict__ hA,
                                              float* __restrict__ hB) {
    const int j   = threadIdx.x;           // output column [0,256)
    const int rp0 = blockIdx.x * 8;        // 56 blocks
    const float* __restrict__ per = pe + (size_t)rp0 * PED;
    float accA[8] = {0.f, 0.f, 0.f, 0.f, 0.f, 0.f, 0.f, 0.f};
    float accB[8] = {0.f, 0.f, 0.f, 0.f, 0.f, 0.f, 0.f, 0.f};
#pragma unroll 4
    for (int k = 0; k < PED; ++k) {
        float wa = WA1[k * 256 + j];
        float wb = WB1[k * 256 + j];
#pragma unroll
        for (int r = 0; r < 8; ++r) {
            float p = per[r * PED + k];    // lane-invariant -> s_load
            accA[r] = fmaf(p, wa, accA[r]);
            accB[r] = fmaf(p, wb, accB[r]);
        }
    }
    float ba = bA1[j], bb = bB1[j];
#pragma unroll
    for (int r = 0; r < 8; ++r) {
        hA[(size_t)(rp0 + r) * 256 + j] = gelu_erf(accA[r] + ba);
        hB[(size_t)(rp0 + r) * 256 + j] = gelu_erf(accB[r] + bb);
    }
}

// K3: A_base = hA @ WA2 + bA2, B_base = hB @ WB2 + bB2   (448x256 @ 256x1024)
__global__ __launch_bounds__(256) void k_dec2(const float* __restrict__ hA,
                                              const float* __restrict__ hB,
                                              const float* __restrict__ WA2,
                                              const float* __restrict__ bA2,
                                              const float* __restrict__ WB2,
                                              const float* __restrict__ bB2,
                                              float* __restrict__ Ab,
                                              float* __restrict__ Bb) {
    const int j   = blockIdx.x * 256 + threadIdx.x;   // [0,1024)
    const int rp0 = blockIdx.y * 8;                   // 56 row-groups
    const float* __restrict__ hAr = hA + (size_t)rp0 * 256;
    const float* __restrict__ hBr = hB + (size_t)rp0 * 256;
    float accA[8] = {0.f, 0.f, 0.f, 0.f, 0.f, 0.f, 0.f, 0.f};
    float accB[8] = {0.f, 0.f, 0.f, 0.f, 0.f, 0.f, 0.f, 0.f};
#pragma unroll 4
    for (int k = 0; k < 256; ++k) {
        float wa = WA2[k * 1024 + j];
        float wb = WB2[k * 1024 + j];
#pragma unroll
        for (int r = 0; r < 8; ++r) {
            float pa = hAr[r * 256 + k];   // lane-invariant -> s_load
            float pb = hBr[r * 256 + k];
            accA[r] = fmaf(pa, wa, accA[r]);
            accB[r] = fmaf(pb, wb, accB[r]);
        }
    }
    float ba = bA2[j], bb = bB2[j];
#pragma unroll
    for (int r = 0; r < 8; ++r) {
        Ab[(size_t)(rp0 + r) * 1024 + j] = accA[r] + ba;
        Bb[(size_t)(rp0 + r) * 1024 + j] = accB[r] + bb;
    }
}

// K4: scatter/tile into the output.
// y = b*224 + l*7 + t.  A piece: 16 x in_d with col j -> A_base[r][j%64]*scA
// B piece: out_d x 16 with row i -> B_base[i%64][j]*scB
__global__ __launch_bounds__(256) void k_scatter(const float* __restrict__ Ab,
                                                 const float* __restrict__ Bb,
                                                 const float* __restrict__ scales,
                                                 float* __restrict__ out) {
    const int y  = blockIdx.y;
    const int t  = y % 7;
    const int lb = y / 7;          // b*32 + l
    const int l  = lb & 31;
    const int b  = lb >> 5;

    int in_d = (t == 6) ? 11008 : 4096;
    int out_d, poff;
    switch (t) {
        case 0:  out_d = 4096;  poff = 0;      break;
        case 1:  out_d = 1024;  poff = 131072; break;
        case 2:  out_d = 1024;  poff = 212992; break;
        case 3:  out_d = 4096;  poff = 294912; break;
        case 4:  out_d = 11008; poff = 425984; break;
        case 5:  out_d = 11008; poff = 667648; break;
        default: out_d = 4096;  poff = 909312; break;
    }
    const float scA = scales[((l * 7 + t) << 1)];
    const float scB = scales[((l * 7 + t) << 1) | 1];
    const float* __restrict__ Arow = Ab + (size_t)y * 1024;
    const float* __restrict__ Brow = Bb + (size_t)y * 1024;

    __shared__ float As[1024];
    __shared__ float Bs[1024];
    for (int i = threadIdx.x; i < 1024; i += 256) {
        As[i] = Arow[i] * scA;
        Bs[i] = Brow[i] * scB;
    }
    __syncthreads();
    const float4* As4 = (const float4*)As;
    const float4* Bs4 = (const float4*)Bs;

    const size_t base4 = ((size_t)b * 36831232u + (size_t)l * 1150976u + (size_t)poff) >> 2;
    float4* __restrict__ dst = (float4*)out + base4;

    const int nA4   = in_d << 2;               // float4 count of A piece
    const int nAll4 = (in_d + out_d) << 2;     // total float4 count of piece
    const int stride = gridDim.x * 256;
    const bool p2 = (in_d == 4096);

    for (int e4 = blockIdx.x * 256 + threadIdx.x; e4 < nAll4; e4 += stride) {
        if (e4 < nA4) {
            // r = e4 / (in_d/4); (e4 % (in_d/4)) % 16 == e4 % 16 (16 | in_d/4)
            int r = p2 ? (e4 >> 10)
                       : (int)(((unsigned)(e4 >> 6) * 1525u) >> 16);  // /43 magic, exact for x<1680
            dst[e4] = As4[(r << 4) | (e4 & 15)];
        } else {
            int f = e4 - nA4;
            dst[e4] = Bs4[(((f >> 2) & 63) << 2) | (f & 3)];
        }
    }
}

extern "C" void kernel_launch(void* const* d_in, const int* in_sizes, int n_in,
                              void* d_out, int out_size, void* d_ws, size_t ws_size,
                              hipStream_t stream) {
    const float* cond   = (const float*)d_in[0];
    const float* Wp     = (const float*)d_in[1];
    const float* bproj  = (const float*)d_in[2];
    const float* WA1    = (const float*)d_in[3];
    const float* bA1    = (const float*)d_in[4];
    const float* WA2    = (const float*)d_in[5];
    const float* bA2    = (const float*)d_in[6];
    const float* WB1    = (const float*)d_in[7];
    const float* bB1    = (const float*)d_in[8];
    const float* WB2    = (const float*)d_in[9];
    const float* bB2    = (const float*)d_in[10];
    const float* scales = (const float*)d_in[11];
    float* out = (float*)d_out;
    float* ws  = (float*)d_ws;

    float* part = ws + OFF_PART;
    float* pe   = ws + OFF_PE;
    float* hA   = ws + OFF_HA;
    float* hB   = ws + OFF_HB;
    float* Ab   = ws + OFF_AB;
    float* Bb   = ws + OFF_BB;

    hipLaunchKernelGGL(k_gemv,    dim3(112, NCH), dim3(256), 0, stream, cond, Wp, part);
    hipLaunchKernelGGL(k_reduce,  dim3(112, 2),   dim3(256), 0, stream, part, bproj, pe);
    hipLaunchKernelGGL(k_dec1,    dim3(56),       dim3(256), 0, stream, pe, WA1, bA1, WB1, bB1, hA, hB);
    hipLaunchKernelGGL(k_dec2,    dim3(4, 56),    dim3(256), 0, stream, hA, hB, WA2, bA2, WB2, bB2, Ab, Bb);
    hipLaunchKernelGGL(k_scatter, dim3(16, 448),  dim3(256), 0, stream, Ab, Bb, scales, out);
}

// Round 2
// 208.405 us; speedup vs baseline: 1.1142x; 1.1142x over previous
//
#include <hip/hip_runtime.h>
#include <math.h>

// ---- problem constants ----
#define NCOL   114688      // P*PED = 224*512
#define NCOL4  28672       // NCOL/4
#define KTOT   384         // EMB
#define NCH    16          // k-chunks for the GEMV
#define KCH    24          // KTOT/NCH
#define NROWS  448         // B * 224
#define PED    512

// ws layout (floats)
#define OFF_PART 0
#define OFF_AB   (NCH * 2 * NCOL)          // 3,670,016
#define OFF_BB   (OFF_AB + NROWS * 1024)   // 4,128,768
// total: 4,587,520 floats = 18.35 MB

// K1: partial GEMV  part[ch][b][col] = sum_{k in chunk} cond[b][k] * W[k][col]
__global__ __launch_bounds__(256) void k_gemv(const float* __restrict__ cond,
                                              const float* __restrict__ W,
                                              float* __restrict__ part) {
    const int col4 = blockIdx.x * 256 + threadIdx.x;   // [0, 28672)
    const int ch   = blockIdx.y;
    const int k0   = ch * KCH;
    __shared__ float cs[2 * KCH];
    if (threadIdx.x < 2 * KCH) {
        int b  = threadIdx.x / KCH;
        int kk = threadIdx.x - b * KCH;
        cs[threadIdx.x] = cond[b * KTOT + k0 + kk];
    }
    __syncthreads();
    const float4* __restrict__ W4 = (const float4*)W;
    float4 a0 = make_float4(0.f, 0.f, 0.f, 0.f);
    float4 a1 = make_float4(0.f, 0.f, 0.f, 0.f);
#pragma unroll 8
    for (int kk = 0; kk < KCH; ++kk) {
        float4 w = W4[(size_t)(k0 + kk) * NCOL4 + col4];
        float c0 = cs[kk];
        float c1 = cs[KCH + kk];
        a0.x = fmaf(c0, w.x, a0.x); a0.y = fmaf(c0, w.y, a0.y);
        a0.z = fmaf(c0, w.z, a0.z); a0.w = fmaf(c0, w.w, a0.w);
        a1.x = fmaf(c1, w.x, a1.x); a1.y = fmaf(c1, w.y, a1.y);
        a1.z = fmaf(c1, w.z, a1.z); a1.w = fmaf(c1, w.w, a1.w);
    }
    float4* p4 = (float4*)part;
    p4[((size_t)ch * 2 + 0) * NCOL4 + col4] = a0;
    p4[((size_t)ch * 2 + 1) * NCOL4 + col4] = a1;
}

__device__ __forceinline__ float gelu_erf(float x) {
    return 0.5f * x * (1.0f + erff(x * 0.70710678118654752440f));
}

// K2: fused reduce + dec1 + dec2 (+bias +scale). 2 rows per block, 224 blocks.
// pe and h live in LDS; outputs scaled Ab/Bb rows (448 x 1024 each).
__global__ __launch_bounds__(256) void k_fused(const float* __restrict__ part,
                                               const float* __restrict__ bproj,
                                               const float* __restrict__ WA1,
                                               const float* __restrict__ bA1,
                                               const float* __restrict__ WA2,
                                               const float* __restrict__ bA2,
                                               const float* __restrict__ WB1,
                                               const float* __restrict__ bB1,
                                               const float* __restrict__ WB2,
                                               const float* __restrict__ bB2,
                                               const float* __restrict__ scales,
                                               float* __restrict__ Ab,
                                               float* __restrict__ Bb) {
    const int tid = threadIdx.x;
    const int y0  = blockIdx.x * 2;        // rows y0, y0+1 (same b: 224 even)
    const int b   = y0 / 224;
    const int p0  = y0 - b * 224;          // = l*7+t for row 0; row 1 is p0+1

    __shared__ float pe_s[2][512];
    __shared__ float hA_s[2][256];
    __shared__ float hB_s[2][256];

    // stage 0: reduce partials -> pe rows (float4 per thread)
    {
        const int r  = tid >> 7;
        const int c4 = tid & 127;
        const size_t colbase = (size_t)(p0 + r) * 128 + c4;
        const float4* __restrict__ p4 = (const float4*)part;
        float4 s = ((const float4*)bproj)[colbase];
#pragma unroll
        for (int ch = 0; ch < NCH; ++ch) {
            float4 v = p4[((size_t)ch * 2 + b) * NCOL4 + colbase];
            s.x += v.x; s.y += v.y; s.z += v.z; s.w += v.w;
        }
        ((float4*)pe_s)[tid] = s;
    }
    __syncthreads();

    // stage 1: dec1 (448x512 @ 512x256), j = tid
    {
        const int j = tid;
        float a0 = 0.f, a1 = 0.f, c0 = 0.f, c1 = 0.f;
#pragma unroll 8
        for (int k = 0; k < 512; ++k) {
            float wa = WA1[k * 256 + j];
            float wb = WB1[k * 256 + j];
            float q0 = pe_s[0][k];
            float q1 = pe_s[1][k];
            a0 = fmaf(q0, wa, a0); a1 = fmaf(q1, wa, a1);
            c0 = fmaf(q0, wb, c0); c1 = fmaf(q1, wb, c1);
        }
        const float ba = bA1[j], bb = bB1[j];
        hA_s[0][j] = gelu_erf(a0 + ba);
        hA_s[1][j] = gelu_erf(a1 + ba);
        hB_s[0][j] = gelu_erf(c0 + bb);
        hB_s[1][j] = gelu_erf(c1 + bb);
    }
    __syncthreads();

    // stage 2: dec2 (448x256 @ 256x1024), thread owns float4 column j4 = tid
    {
        float4 aA0 = make_float4(0.f, 0.f, 0.f, 0.f);
        float4 aA1 = make_float4(0.f, 0.f, 0.f, 0.f);
        float4 aB0 = make_float4(0.f, 0.f, 0.f, 0.f);
        float4 aB1 = make_float4(0.f, 0.f, 0.f, 0.f);
        const float4* __restrict__ WA2_4 = (const float4*)WA2;
        const float4* __restrict__ WB2_4 = (const float4*)WB2;
#pragma unroll 4
        for (int k = 0; k < 256; ++k) {
            float4 wa = WA2_4[k * 256 + tid];
            float4 wb = WB2_4[k * 256 + tid];
            float hA0 = hA_s[0][k], hA1 = hA_s[1][k];
            float hB0 = hB_s[0][k], hB1 = hB_s[1][k];
            aA0.x = fmaf(hA0, wa.x, aA0.x); aA0.y = fmaf(hA0, wa.y, aA0.y);
            aA0.z = fmaf(hA0, wa.z, aA0.z); aA0.w = fmaf(hA0, wa.w, aA0.w);
            aA1.x = fmaf(hA1, wa.x, aA1.x); aA1.y = fmaf(hA1, wa.y, aA1.y);
            aA1.z = fmaf(hA1, wa.z, aA1.z); aA1.w = fmaf(hA1, wa.w, aA1.w);
            aB0.x = fmaf(hB0, wb.x, aB0.x); aB0.y = fmaf(hB0, wb.y, aB0.y);
            aB0.z = fmaf(hB0, wb.z, aB0.z); aB0.w = fmaf(hB0, wb.w, aB0.w);
            aB1.x = fmaf(hB1, wb.x, aB1.x); aB1.y = fmaf(hB1, wb.y, aB1.y);
            aB1.z = fmaf(hB1, wb.z, aB1.z); aB1.w = fmaf(hB1, wb.w, aB1.w);
        }
        const float4 ba = ((const float4*)bA2)[tid];
        const float4 bb = ((const float4*)bB2)[tid];
        const float scA0 = scales[p0 * 2],       scB0 = scales[p0 * 2 + 1];
        const float scA1 = scales[(p0 + 1) * 2], scB1 = scales[(p0 + 1) * 2 + 1];
        float4* __restrict__ Ab4 = (float4*)Ab;
        float4* __restrict__ Bb4 = (float4*)Bb;
        float4 o;
        o.x = (aA0.x + ba.x) * scA0; o.y = (aA0.y + ba.y) * scA0;
        o.z = (aA0.z + ba.z) * scA0; o.w = (aA0.w + ba.w) * scA0;
        Ab4[(size_t)y0 * 256 + tid] = o;
        o.x = (aA1.x + ba.x) * scA1; o.y = (aA1.y + ba.y) * scA1;
        o.z = (aA1.z + ba.z) * scA1; o.w = (aA1.w + ba.w) * scA1;
        Ab4[(size_t)(y0 + 1) * 256 + tid] = o;
        o.x = (aB0.x + bb.x) * scB0; o.y = (aB0.y + bb.y) * scB0;
        o.z = (aB0.z + bb.z) * scB0; o.w = (aB0.w + bb.w) * scB0;
        Bb4[(size_t)y0 * 256 + tid] = o;
        o.x = (aB1.x + bb.x) * scB1; o.y = (aB1.y + bb.y) * scB1;
        o.z = (aB1.z + bb.z) * scB1; o.w = (aB1.w + bb.w) * scB1;
        Bb4[(size_t)(y0 + 1) * 256 + tid] = o;
    }
}

// K3: scatter/tile into the output (pure copy; scales already applied).
__global__ __launch_bounds__(256) void k_scatter(const float* __restrict__ Ab,
                                                 const float* __restrict__ Bb,
                                                 float* __restrict__ out) {
    const int y  = blockIdx.y;
    const int t  = y % 7;
    const int lb = y / 7;          // b*32 + l
    const int l  = lb & 31;
    const int b  = lb >> 5;

    int in_d = (t == 6) ? 11008 : 4096;
    int out_d, poff;
    switch (t) {
        case 0:  out_d = 4096;  poff = 0;      break;
        case 1:  out_d = 1024;  poff = 131072; break;
        case 2:  out_d = 1024;  poff = 212992; break;
        case 3:  out_d = 4096;  poff = 294912; break;
        case 4:  out_d = 11008; poff = 425984; break;
        case 5:  out_d = 11008; poff = 667648; break;
        default: out_d = 4096;  poff = 909312; break;
    }
    __shared__ float4 As4[256];
    __shared__ float4 Bs4[256];
    const float4* __restrict__ Arow4 = (const float4*)Ab + (size_t)y * 256;
    const float4* __restrict__ Brow4 = (const float4*)Bb + (size_t)y * 256;
    As4[threadIdx.x] = Arow4[threadIdx.x];
    Bs4[threadIdx.x] = Brow4[threadIdx.x];
    __syncthreads();

    const size_t base4 = ((size_t)b * 36831232u + (size_t)l * 1150976u + (size_t)poff) >> 2;
    float4* __restrict__ dst = (float4*)out + base4;

    const int nA4    = in_d << 2;               // float4 count of A piece
    const int nAll4  = (in_d + out_d) << 2;     // total float4 count of piece
    const int stride = gridDim.x * 256;
    const bool p2 = (in_d == 4096);

    for (int e4 = blockIdx.x * 256 + threadIdx.x; e4 < nAll4; e4 += stride) {
        if (e4 < nA4) {
            // r = e4 / (in_d/4); within-row float4 = e4 % 16 (16 | in_d/4)
            int r = p2 ? (e4 >> 10)
                       : (int)(((unsigned)(e4 >> 6) * 1525u) >> 16);  // /43 magic, exact for x<1680
            dst[e4] = As4[(r << 4) | (e4 & 15)];
        } else {
            int f = e4 - nA4;
            dst[e4] = Bs4[(((f >> 2) & 63) << 2) | (f & 3)];
        }
    }
}

extern "C" void kernel_launch(void* const* d_in, const int* in_sizes, int n_in,
                              void* d_out, int out_size, void* d_ws, size_t ws_size,
                              hipStream_t stream) {
    const float* cond   = (const float*)d_in[0];
    const float* Wp     = (const float*)d_in[1];
    const float* bproj  = (const float*)d_in[2];
    const float* WA1    = (const float*)d_in[3];
    const float* bA1    = (const float*)d_in[4];
    const float* WA2    = (const float*)d_in[5];
    const float* bA2    = (const float*)d_in[6];
    const float* WB1    = (const float*)d_in[7];
    const float* bB1    = (const float*)d_in[8];
    const float* WB2    = (const float*)d_in[9];
    const float* bB2    = (const float*)d_in[10];
    const float* scales = (const float*)d_in[11];
    float* out = (float*)d_out;
    float* ws  = (float*)d_ws;

    float* part = ws + OFF_PART;
    float* Ab   = ws + OFF_AB;
    float* Bb   = ws + OFF_BB;

    hipLaunchKernelGGL(k_gemv,    dim3(112, NCH), dim3(256), 0, stream, cond, Wp, part);
    hipLaunchKernelGGL(k_fused,   dim3(224),      dim3(256), 0, stream,
                       part, bproj, WA1, bA1, WA2, bA2, WB1, bB1, WB2, bB2, scales, Ab, Bb);
    hipLaunchKernelGGL(k_scatter, dim3(16, 448),  dim3(256), 0, stream, Ab, Bb, out);
}